// Round 4
// baseline (272.624 us; speedup 1.0000x reference)
//
#include <hip/hip_runtime.h>
#include <math.h>

#define MAXC 16              // max_num_children (reference MAX_CHILDREN)
#define GPB  256             // groups per chunk
#define BLOCK 256
#define PFV 3                // float4 score-prefetch regs/thread (covers span<=3072; typical ~2340)
#define PFG 2                // uint4 gid-prefetch regs/thread (8 gids each; covers <=4096 elems)
#define LBUF_SZ (GPB*MAXC + 24)   // span + align pad + compute over-read pad
#define GBUF_SZ (GPB*MAXC + 16)

// Barrier with LDS-only ordering: does NOT drain vmcnt, so prefetch global
// loads stay in flight across it (unlike __syncthreads, which emits
// s_waitcnt vmcnt(0) before s_barrier — the m97-style structural stall).
__device__ __forceinline__ void lds_barrier() {
    asm volatile("s_waitcnt lgkmcnt(0)" ::: "memory");
    __builtin_amdgcn_s_barrier();
}

// Kernel 1: per-group start offsets + per-element group id (uint16).
__global__ void build_meta_kernel(const int* __restrict__ flat_index,
                                  const int* __restrict__ p_num_internal,
                                  const int* __restrict__ p_max_children,
                                  int n_scores,
                                  int* __restrict__ offs,
                                  unsigned short* __restrict__ gid16) {
    int j = blockIdx.x * blockDim.x + threadIdx.x;
    int mc = p_max_children[0];
    if (j < n_scores) {
        int fi = flat_index[j];
        int g  = fi / mc;
        gid16[j] = (unsigned short)g;
        if (fi - g * mc == 0) offs[g] = j;
    }
    if (j == 0) offs[p_num_internal[0]] = n_scores;
}

// Kernel 2: grouped log-softmax, software-pipelined over chunks.
// out[b,0] = 0 ; out[b, 1+j] = scores[b,j] - logsumexp(group(j)).
__global__ void __launch_bounds__(BLOCK, 6)
hier_logsoftmax_kernel(const float* __restrict__ scores,
                       const int* __restrict__ offs,
                       const unsigned short* __restrict__ gid16,
                       const int* __restrict__ p_num_internal,
                       float* __restrict__ out,
                       int n_scores, int num_nodes, int batch) {
    __shared__ __align__(16) float lbuf[LBUF_SZ];
    __shared__ __align__(16) unsigned short gbuf[GBUF_SZ];
    __shared__ float lsebuf[GPB];

    const int ni = p_num_internal[0];
    const int nchunks = (ni + GPB - 1) / GPB;
    if ((int)blockIdx.x >= nchunks) return;

    const int b = blockIdx.y;
    const float* __restrict__ srow = scores + (size_t)b * (size_t)n_scores;
    float* __restrict__ orow = out + (size_t)b * (size_t)num_nodes;
    const int slim = (batch - b) * n_scores;   // elements readable from srow (stay inside array)

    int chunk = blockIdx.x;

    // ---- prefetch state (registers) ----
    int g0, gend, e0, e1, ea4, ea8, nv4, nvg, ogt = 0, og1t = 0;
    float4 pv[PFV];
    uint4  pg[PFG];

    auto do_prefetch = [&](int c) {
        g0 = c * GPB; gend = min(g0 + GPB, ni);
        e0 = offs[g0]; e1 = offs[gend];
        ea4 = e0 & ~3; ea8 = e0 & ~7;           // row-relative alignment bases
        nv4 = (e1 - ea4 + 3) >> 2;
        nvg = (e1 - ea8 + 7) >> 3;
#pragma unroll
        for (int p = 0; p < PFV; ++p) {
            const int q = (int)threadIdx.x + p * BLOCK;
            const int base = ea4 + 4 * q;
            float4 t = make_float4(0.f, 0.f, 0.f, 0.f);
            if (q < nv4) {
                if (base + 4 <= slim) {
                    t = *(const float4*)(srow + base);       // dword-aligned: OK on gfx950
                } else {
                    if (base     < slim) t.x = srow[base];
                    if (base + 1 < slim) t.y = srow[base + 1];
                    if (base + 2 < slim) t.z = srow[base + 2];
                    if (base + 3 < slim) t.w = srow[base + 3];
                }
            }
            pv[p] = t;
        }
#pragma unroll
        for (int p = 0; p < PFG; ++p) {
            const int q = (int)threadIdx.x + p * BLOCK;
            const int base = ea8 + 8 * q;
            uint4 t = make_uint4(0u, 0u, 0u, 0u);
            if (q < nvg) {
                if (base + 8 <= n_scores) {
                    t = *(const uint4*)(gid16 + base);       // 16B-aligned (ea8 mult of 8)
                } else {
                    unsigned w0 = 0, w1 = 0, w2 = 0, w3 = 0;
                    if (base + 0 < n_scores) w0 |= (unsigned)gid16[base + 0];
                    if (base + 1 < n_scores) w0 |= (unsigned)gid16[base + 1] << 16;
                    if (base + 2 < n_scores) w1 |= (unsigned)gid16[base + 2];
                    if (base + 3 < n_scores) w1 |= (unsigned)gid16[base + 3] << 16;
                    if (base + 4 < n_scores) w2 |= (unsigned)gid16[base + 4];
                    if (base + 5 < n_scores) w2 |= (unsigned)gid16[base + 5] << 16;
                    if (base + 6 < n_scores) w3 |= (unsigned)gid16[base + 6];
                    if (base + 7 < n_scores) w3 |= (unsigned)gid16[base + 7] << 16;
                    t = make_uint4(w0, w1, w2, w3);
                }
            }
            pg[p] = t;
        }
        const int g = g0 + (int)threadIdx.x;
        if (g < gend) { ogt = offs[g]; og1t = offs[g + 1]; }   // group bounds for compute
    };

    do_prefetch(chunk);

    for (;;) {
        lds_barrier();   // prior store phase done reading lbuf/gbuf/lsebuf

        // ---- fill phase: prefetched regs -> LDS ----
#pragma unroll
        for (int p = 0; p < PFV; ++p) {
            const int q = (int)threadIdx.x + p * BLOCK;
            if (q < nv4) *(float4*)&lbuf[4 * q] = pv[p];
        }
        for (int q = PFV * BLOCK + (int)threadIdx.x; q < nv4; q += BLOCK) {  // rare overflow
            const int base = ea4 + 4 * q;
            float4 t = make_float4(0.f, 0.f, 0.f, 0.f);
            if (base + 4 <= slim) t = *(const float4*)(srow + base);
            else {
                if (base     < slim) t.x = srow[base];
                if (base + 1 < slim) t.y = srow[base + 1];
                if (base + 2 < slim) t.z = srow[base + 2];
                if (base + 3 < slim) t.w = srow[base + 3];
            }
            *(float4*)&lbuf[4 * q] = t;
        }
#pragma unroll
        for (int p = 0; p < PFG; ++p) {
            const int q = (int)threadIdx.x + p * BLOCK;
            if (q < nvg) *(uint4*)&gbuf[8 * q] = pg[p];
        }
        for (int q = PFG * BLOCK + (int)threadIdx.x; q < nvg; q += BLOCK) {  // rare overflow
            const int base = ea8 + 8 * q;
            uint4 t = make_uint4(0u, 0u, 0u, 0u);
            if (base + 8 <= n_scores) t = *(const uint4*)(gid16 + base);
            *(uint4*)&gbuf[8 * q] = t;
        }

        // stash current-chunk geometry; then launch next chunk's prefetch so its
        // global loads fly across this chunk's compute + store phases.
        const int cg0 = g0, cgend = gend, ce0 = e0, ce1 = e1;
        const int cea4 = ea4, cea8 = ea8, cog = ogt, cog1 = og1t;
        const int next = chunk + gridDim.x;
        const bool have_next = next < nchunks;
        if (have_next) do_prefetch(next);

        lds_barrier();   // lbuf/gbuf visible to all waves

        // ---- compute phase: one thread per group -> lse ----
        {
            const int g = cg0 + (int)threadIdx.x;
            if (g < cgend) {
                const int lo = cog - cea4;
                const int c  = cog1 - cog;          // 2..MAXC
                float v[MAXC];
#pragma unroll
                for (int k = 0; k < MAXC; ++k)
                    v[k] = (k < c) ? lbuf[lo + k] : -INFINITY;
                float m = v[0];
#pragma unroll
                for (int k = 1; k < MAXC; ++k) m = fmaxf(m, v[k]);
                float s = 0.0f;
#pragma unroll
                for (int k = 0; k < MAXC; ++k) s += __expf(v[k] - m);   // exp(-inf)=0 pads
                lsebuf[threadIdx.x] = m + __logf(s);
            }
        }

        lds_barrier();   // lsebuf visible

        // ---- store phase: out = staged - lse[gid], coalesced float4 ----
        {
            const int n  = ce1 - ce0;
            const int hS = min(n, (4 - ((1 + ce0) & 3)) & 3);
            if ((int)threadIdx.x < hS) {
                const int e = ce0 + (int)threadIdx.x;
                orow[1 + e] = lbuf[e - cea4] - lsebuf[gbuf[e - cea8] - cg0];
            }
            const int nvS = (n - hS) >> 2;
            for (int q = (int)threadIdx.x; q < nvS; q += BLOCK) {
                const int e = ce0 + hS + 4 * q;
                float4 t;
                t.x = lbuf[e     - cea4] - lsebuf[gbuf[e     - cea8] - cg0];
                t.y = lbuf[e + 1 - cea4] - lsebuf[gbuf[e + 1 - cea8] - cg0];
                t.z = lbuf[e + 2 - cea4] - lsebuf[gbuf[e + 2 - cea8] - cg0];
                t.w = lbuf[e + 3 - cea4] - lsebuf[gbuf[e + 3 - cea8] - cg0];
                *(float4*)&orow[1 + e] = t;
            }
            for (int i = hS + 4 * nvS + (int)threadIdx.x; i < n; i += BLOCK) {
                const int e = ce0 + i;
                orow[1 + e] = lbuf[e - cea4] - lsebuf[gbuf[e - cea8] - cg0];
            }
            if (chunk == 0 && threadIdx.x == 0) orow[0] = 0.0f;   // root stays 0
        }

        if (!have_next) break;
        chunk = next;
    }
}

extern "C" void kernel_launch(void* const* d_in, const int* in_sizes, int n_in,
                              void* d_out, int out_size, void* d_ws, size_t ws_size,
                              hipStream_t stream) {
    const float* scores     = (const float*)d_in[0];
    const int*   flat_index = (const int*)d_in[1];
    // d_in[2] = child_index (== arange(1,num_nodes), not needed)
    const int*   p_ni       = (const int*)d_in[3];  // num_internal (device scalar)
    const int*   p_mc       = (const int*)d_in[4];  // max_num_children (device scalar)

    const int n_scores  = in_sizes[1];
    const int batch     = in_sizes[0] / n_scores;
    const int num_nodes = out_size / batch;

    // Workspace: offs (<= n_scores+1 ints), then gid16 (n_scores u16), 256B-aligned split.
    int* offs = (int*)d_ws;
    unsigned short* gid16 =
        (unsigned short*)((char*)d_ws + (((size_t)(n_scores + 2) * 4 + 255) & ~(size_t)255));
    float* out = (float*)d_out;

    // Kernel 1: build group offsets + per-element gid.
    {
        dim3 blk(256), grd((n_scores + 255) / 256);
        hipLaunchKernelGGL(build_meta_kernel, grd, blk, 0, stream,
                           flat_index, p_ni, p_mc, n_scores, offs, gid16);
    }

    // Kernel 2: pipelined main compute. grid.x=4 -> each block handles ~4 chunks
    // (block-stride loop covers any device-side chunk count).
    {
        dim3 blk(BLOCK), grd(4, batch);
        hipLaunchKernelGGL(hier_logsoftmax_kernel, grd, blk, 0, stream,
                           scores, offs, gid16, p_ni, out, n_scores, num_nodes, batch);
    }
}